// Round 8
// baseline (1871.767 us; speedup 1.0000x reference)
//
#include <hip/hip_runtime.h>
#include <stdint.h>

// x: (B=4, C=64, N=8192, 1) fp32. Output edge_index int32 (2,B,N,9).
#define NB 4
#define NC 64
#define NPTS 8192
#define KK 18          // K * DILATION
#define KOUT 9         // kept after ::2
#define ROWS 16        // rows (n) per block
#define TM 128         // m-tile width

// Monotone float->uint32 map (total order incl. negatives).
static __device__ __forceinline__ unsigned fkey(float d) {
    unsigned fb = __float_as_uint(d);
    fb ^= ((unsigned)((int)fb >> 31)) | 0x80000000u;
    return fb;
}

// ---------------------------------------------------------------------------
// Kernel 1: normalize, matching numpy bit-exactly.
//   norm: reduce over axis=1 (outer axis) -> sequential c accumulation
//   pts = x / max(norm,1e-12)
//   sq = np.sum(t, axis=-1), t = pts*pts contiguous len-64:
//     numpy reduce SEEDS with t0 (skip_first_count), then pairwise_sum over
//     the remaining n=63 (scalar 8-acc path since 63 < nlanes*8):
//       r_j = t_{1+j}; r_j += t_{1+8k+j} for k=1..6   (covers t1..t56)
//       res = ((r0+r1)+(r2+r3)) + ((r4+r5)+(r6+r7))
//       res += t57 ... += t63                          (sequential tail)
//       sq  = t0 + res
// ---------------------------------------------------------------------------
__global__ __launch_bounds__(256) void normalize_kernel(
    const float* __restrict__ x, float* __restrict__ pts, float* __restrict__ sq) {
#pragma clang fp contract(off)
    int idx = blockIdx.x * 256 + threadIdx.x;   // b*NPTS + n
    if (idx >= NB * NPTS) return;
    int b = idx / NPTS, n = idx % NPTS;
    const float* xb = x + (size_t)b * NC * NPTS + n;

    float acc = 0.f;
    #pragma unroll
    for (int c = 0; c < NC; ++c) {
        float v = xb[(size_t)c * NPTS];
        acc = __fadd_rn(acc, __fmul_rn(v, v));
    }
    float nm = fmaxf(__fsqrt_rn(acc), 1e-12f);

    float t[NC];
    #pragma unroll
    for (int c = 0; c < NC; ++c) {
        float p = __fdiv_rn(xb[(size_t)c * NPTS], nm);
        pts[((size_t)b * NC + c) * NPTS + n] = p;
        t[c] = __fmul_rn(p, p);
    }
    // seed-skip pairwise: q[i] = t[1+i], n = 63
    float r[8];
    #pragma unroll
    for (int j = 0; j < 8; ++j) r[j] = t[1 + j];
    #pragma unroll
    for (int i = 8; i < 56; i += 8)
        #pragma unroll
        for (int j = 0; j < 8; ++j) r[j] = __fadd_rn(r[j], t[1 + i + j]);
    float res = __fadd_rn(__fadd_rn(__fadd_rn(r[0], r[1]), __fadd_rn(r[2], r[3])),
                          __fadd_rn(__fadd_rn(r[4], r[5]), __fadd_rn(r[6], r[7])));
    #pragma unroll
    for (int i = 57; i < NC; ++i) res = __fadd_rn(res, t[i]);
    sq[idx] = __fadd_rn(t[0], res);
}

// ---------------------------------------------------------------------------
// Kernel 2 (identical to best-so-far B): dot = einsum m-inner SOP semantics:
// per (n,m): sequential over c ascending, acc = fadd(fmul(a,b), acc), non-FMA.
// dist = (sq_n + (-2*dot)) + sq_m.
// Online top-18 per row via uint64 key = (fkey(dist)<<32) | m  (ties lower-first).
// ---------------------------------------------------------------------------
__global__ __launch_bounds__(256) void knn_kernel(
    const float* __restrict__ pts, const float* __restrict__ sq, int* __restrict__ out) {
#pragma clang fp contract(off)
    __shared__ float sA[NC][ROWS];                 // A tile [c][r]   4 KB
    __shared__ float sB[NC][TM];                   // B tile [c][m]  32 KB
    __shared__ float sSqB[TM];
    __shared__ float sSqA[ROWS];
    __shared__ unsigned long long listK[ROWS][KK];
    __shared__ unsigned long long pendK[ROWS][TM];
    __shared__ int pendCnt[ROWS];

    const int tid  = threadIdx.x;
    const int blk  = blockIdx.x;
    const int b    = blk / (NPTS / ROWS);
    const int row0 = (blk % (NPTS / ROWS)) * ROWS;
    const float* P = pts + (size_t)b * NC * NPTS;

    if (tid < ROWS) {
        sSqA[tid] = sq[b * NPTS + row0 + tid];
        pendCnt[tid] = 0;
    }
    for (int i = tid; i < ROWS * KK; i += 256)
        ((unsigned long long*)listK)[i] = 0xFFFFFFFFFFFFFFFFULL;
    for (int i = tid; i < NC * ROWS; i += 256) {
        int c = i / ROWS, r = i % ROWS;
        sA[c][r] = P[(size_t)c * NPTS + row0 + r];
    }
    __syncthreads();

    const int g = tid >> 6;    // row group (wave-uniform): rows 4g..4g+3
    const int j = tid & 63;    // m lane: local m = 2j, 2j+1
    const float sqa0 = sSqA[4*g+0], sqa1 = sSqA[4*g+1],
                sqa2 = sSqA[4*g+2], sqa3 = sSqA[4*g+3];

    for (int mt = 0; mt < NPTS / TM; ++mt) {
        const int m0 = mt * TM;
        #pragma unroll
        for (int k = 0; k < (NC * TM) / 256; ++k) {
            int i = tid + k * 256;
            int c = i >> 7, m = i & (TM - 1);
            sB[c][m] = P[(size_t)c * NPTS + m0 + m];
        }
        if (tid < TM) sSqB[tid] = sq[b * NPTS + m0 + tid];
        __syncthreads();

        float a00=0,a01=0,a10=0,a11=0,a20=0,a21=0,a30=0,a31=0;
        #pragma unroll 8
        for (int c = 0; c < NC; ++c) {
            const float4 av = *(const float4*)&sA[c][g * 4];
            const float2 bv = *(const float2*)&sB[c][j * 2];
            a00 = __fadd_rn(__fmul_rn(av.x, bv.x), a00);
            a01 = __fadd_rn(__fmul_rn(av.x, bv.y), a01);
            a10 = __fadd_rn(__fmul_rn(av.y, bv.x), a10);
            a11 = __fadd_rn(__fmul_rn(av.y, bv.y), a11);
            a20 = __fadd_rn(__fmul_rn(av.z, bv.x), a20);
            a21 = __fadd_rn(__fmul_rn(av.z, bv.y), a21);
            a30 = __fadd_rn(__fmul_rn(av.w, bv.x), a30);
            a31 = __fadd_rn(__fmul_rn(av.w, bv.y), a31);
        }

        const float sqb0 = sSqB[2*j], sqb1 = sSqB[2*j+1];
        const unsigned m_g0 = (unsigned)(m0 + 2*j), m_g1 = (unsigned)(m0 + 2*j + 1);

        #pragma unroll
        for (int r = 0; r < 4; ++r) {
            float dot0, dot1, sqa;
            if      (r == 0) { dot0 = a00; dot1 = a01; sqa = sqa0; }
            else if (r == 1) { dot0 = a10; dot1 = a11; sqa = sqa1; }
            else if (r == 2) { dot0 = a20; dot1 = a21; sqa = sqa2; }
            else             { dot0 = a30; dot1 = a31; sqa = sqa3; }
            const int row = 4 * g + r;
            const unsigned long long thr = listK[row][KK - 1];

            float d0 = __fadd_rn(__fadd_rn(sqa, __fmul_rn(-2.f, dot0)), sqb0);
            unsigned long long k0 = ((unsigned long long)fkey(d0) << 32) | m_g0;
            if (k0 < thr) { int p = atomicAdd(&pendCnt[row], 1); pendK[row][p] = k0; }

            float d1 = __fadd_rn(__fadd_rn(sqa, __fmul_rn(-2.f, dot1)), sqb1);
            unsigned long long k1 = ((unsigned long long)fkey(d1) << 32) | m_g1;
            if (k1 < thr) { int p = atomicAdd(&pendCnt[row], 1); pendK[row][p] = k1; }
        }
        __syncthreads();

        if (tid < ROWS) {
            const int cnt = pendCnt[tid];
            for (int q = 0; q < cnt; ++q) {
                unsigned long long key = pendK[tid][q];
                if (key < listK[tid][KK - 1]) {
                    int p = KK - 1;
                    while (p > 0 && listK[tid][p - 1] > key) {
                        listK[tid][p] = listK[tid][p - 1];
                        --p;
                    }
                    listK[tid][p] = key;
                }
            }
            pendCnt[tid] = 0;
        }
        __syncthreads();
    }

    if (tid < ROWS) {
        const int n = row0 + tid;
        int* o0 = out + ((size_t)(0 * NB + b) * NPTS + n) * KOUT;
        int* o1 = out + ((size_t)(1 * NB + b) * NPTS + n) * KOUT;
        #pragma unroll
        for (int k = 0; k < KOUT; ++k) {
            o0[k] = (int)(unsigned)(listK[tid][2 * k] & 0xFFFFFFFFULL);
            o1[k] = n;
        }
    }
}

extern "C" void kernel_launch(void* const* d_in, const int* in_sizes, int n_in,
                              void* d_out, int out_size, void* d_ws, size_t ws_size,
                              hipStream_t stream) {
    const float* x = (const float*)d_in[0];
    int* out = (int*)d_out;
    float* pts = (float*)d_ws;                                  // B*C*N fp32 = 8 MB
    float* sq  = (float*)d_ws + (size_t)NB * NC * NPTS;         // B*N fp32

    normalize_kernel<<<(NB * NPTS + 255) / 256, 256, 0, stream>>>(x, pts, sq);
    knn_kernel<<<NB * (NPTS / ROWS), 256, 0, stream>>>(pts, sq, out);
}